// Round 5
// baseline (272.210 us; speedup 1.0000x reference)
//
#include <hip/hip_runtime.h>
#include <stdint.h>

#define CIN   256
#define COUT  128
#define HH    128
#define WW    128
#define NIMG  16

typedef unsigned long long u64;
typedef unsigned int u32;
typedef unsigned short u16;
typedef u32 u32x4 __attribute__((ext_vector_type(4)));

// ---------------------------------------------------------------------------
// Pack sign bits of x: px[(n*HH + h)*WW + w][word 0..3], bit (c&63) of word
// (c>>6) is (x[n][c][h][w] > 0). Position-major, 4 u64 (32 B) per position.
// ---------------------------------------------------------------------------
__global__ __launch_bounds__(256) void pack_x_kernel(const float* __restrict__ x,
                                                     u64* __restrict__ px) {
    int t = blockIdx.x * 256 + threadIdx.x;
    int w = t & (WW - 1);
    int h = (t >> 7) & (HH - 1);
    int n = t >> 14;
    const float* xp = x + (size_t)n * CIN * HH * WW + (size_t)h * WW + w;
    u64 words[4];
#pragma unroll
    for (int wd = 0; wd < 4; ++wd) {
        u64 acc = 0;
#pragma unroll 16
        for (int cc = 0; cc < 64; ++cc) {
            float v = xp[(size_t)(wd * 64 + cc) * (HH * WW)];
            acc |= (u64)(v > 0.0f) << cc;
        }
        words[wd] = acc;
    }
    ulonglong2* o = reinterpret_cast<ulonglong2*>(px + (size_t)t * 4);
    o[0] = make_ulonglong2(words[0], words[1]);
    o[1] = make_ulonglong2(words[2], words[3]);
}

// ---------------------------------------------------------------------------
// Pack weight sign bits, alpha, and full-channel border-correction table.
// pw[co*36 + k*4 + word] (u64, same channel<->bit layout as px).
// corrg[pat*COUT + co] (u16) = sum over taps invalid in border pattern `pat`
// of popcount(w[co][tap]) over all 256 channels. pat = ht*3+wt,
// ht/wt in {0=low border, 1=interior, 2=high border}.
// ---------------------------------------------------------------------------
__global__ __launch_bounds__(256) void pack_w_kernel(const float* __restrict__ wt,
                                                     u64* __restrict__ pw,
                                                     float* __restrict__ alpha,
                                                     u16* __restrict__ corrg) {
    int co = blockIdx.x;
    int c  = threadIdx.x;        // 0..255 = input channel
    int lane = c & 63;
    int word = c >> 6;
    __shared__ u64 wsh[9][4];
    __shared__ u32 pct[9];
    __shared__ float red[4];
    const float* wp = wt + ((size_t)co * CIN + c) * 9;
    float vals[9];
    float asum = 0.0f;
#pragma unroll
    for (int k = 0; k < 9; ++k) { vals[k] = wp[k]; asum += fabsf(vals[k]); }
#pragma unroll
    for (int k = 0; k < 9; ++k) {
        u64 m = __ballot(vals[k] > 0.0f);
        if (lane == 0) { pw[co * 36 + k * 4 + word] = m; wsh[k][word] = m; }
    }
    for (int off = 32; off > 0; off >>= 1) asum += __shfl_down(asum, off);
    if (lane == 0) red[word] = asum;
    __syncthreads();
    if (c < 9)
        pct[c] = __popcll(wsh[c][0]) + __popcll(wsh[c][1]) +
                 __popcll(wsh[c][2]) + __popcll(wsh[c][3]);
    if (c == 0) alpha[co] = (red[0] + red[1] + red[2] + red[3]) * (1.0f / 2304.0f);
    __syncthreads();
    if (c < 9) {
        int pat = c, ht = pat / 3, wtp = pat % 3;
        u32 corr = 0;
#pragma unroll
        for (int k = 0; k < 9; ++k) {
            int dh = k / 3 - 1, dw = k % 3 - 1;
            bool inv = (dh == -1 && ht == 0) || (dh == 1 && ht == 2) ||
                       (dw == -1 && wtp == 0) || (dw == 1 && wtp == 2);
            if (inv) corr += pct[k];
        }
        corrg[pat * COUT + co] = (u16)corr;
    }
}

// ---------------------------------------------------------------------------
// XNOR conv v5. R1-R4 forensics: EVERY round was LDS-pipe-bound, not
// VALU-bound. A wave-uniform broadcast ds_read_b128 costs ~12 cyc of LDS
// pipe but delivers only 16 useful bytes; 18 reads/co-iter x 64 iters x
// 32 waves/CU x 12cyc = ~184us -- exactly the measured 210-225us plateau.
// Fix: weights are wave-uniform per co => stream them through the SCALAR
// pipe (uniform global address -> s_load_dwordx16 into SGPRs; v_xor v,s,v
// consumes the SGPR operand for free). LDS holds only the 2.3KB corr table.
// Inputs: 72 u32/thread via opaque-asm loads (R4-proven residency trick);
// hot loop = 72 v_xor + 72 v_bcnt-accumulate per co. VALU floor ~62us.
// out[n][co][h][w] = (256*nv - 2*mismatch) * alpha[w]   (alpha by WIDTH!)
// ---------------------------------------------------------------------------
__global__ __launch_bounds__(256, 4) void conv_kernel(const u64* __restrict__ px,
                                                      const u64* __restrict__ pw,
                                                      const float* __restrict__ alpha,
                                                      const u16* __restrict__ corrg,
                                                      float* __restrict__ out) {
    __shared__ u16 corrs[9 * COUT];            // 2304 B
    {
        const u32* cs = reinterpret_cast<const u32*>(corrg);
        u32* cd = reinterpret_cast<u32*>(corrs);
        for (int i = threadIdx.x; i < 9 * COUT / 2; i += 256) cd[i] = cs[i];
    }

    int tid = threadIdx.x;
    int w  = tid & (WW - 1);
    int hh = tid >> 7;                 // 0/1: two rows per block
    int bid = blockIdx.x;              // 0..1023 = n*64 + hpair
    int h = ((bid & 63) << 1) | hh;
    int n = bid >> 6;

    u32 off[9];
    u32 vm[9];
    int nv = 0;
#pragma unroll
    for (int dh = -1; dh <= 1; ++dh) {
#pragma unroll
        for (int dw = -1; dw <= 1; ++dw) {
            int k = (dh + 1) * 3 + (dw + 1);
            int hn = h + dh, wn = w + dw;
            bool valid = (hn >= 0) && (hn < HH) && (wn >= 0) && (wn < WW);
            vm[k] = valid ? 0xFFFFFFFFu : 0u;
            nv += valid ? 1 : 0;
            int hc = min(max(hn, 0), HH - 1);
            int wc = min(max(wn, 0), WW - 1);
            off[k] = (u32)(((n * HH + hc) * WW + wc) * 32);
        }
    }

    // Opaque tap loads: 2x dwordx4 per tap (full 256 channels), single wait.
    u32x4 t0, t1, t2, t3, t4, t5, t6, t7, t8, t9, t10, t11, t12, t13, t14, t15, t16, t17;
    asm volatile(
        "global_load_dwordx4 %0, %18, %27\n\t"
        "global_load_dwordx4 %1, %18, %27 offset:16\n\t"
        "global_load_dwordx4 %2, %19, %27\n\t"
        "global_load_dwordx4 %3, %19, %27 offset:16\n\t"
        "global_load_dwordx4 %4, %20, %27\n\t"
        "global_load_dwordx4 %5, %20, %27 offset:16\n\t"
        "global_load_dwordx4 %6, %21, %27\n\t"
        "global_load_dwordx4 %7, %21, %27 offset:16\n\t"
        "global_load_dwordx4 %8, %22, %27\n\t"
        "global_load_dwordx4 %9, %22, %27 offset:16\n\t"
        "global_load_dwordx4 %10, %23, %27\n\t"
        "global_load_dwordx4 %11, %23, %27 offset:16\n\t"
        "global_load_dwordx4 %12, %24, %27\n\t"
        "global_load_dwordx4 %13, %24, %27 offset:16\n\t"
        "global_load_dwordx4 %14, %25, %27\n\t"
        "global_load_dwordx4 %15, %25, %27 offset:16\n\t"
        "global_load_dwordx4 %16, %26, %27\n\t"
        "global_load_dwordx4 %17, %26, %27 offset:16\n\t"
        "s_waitcnt vmcnt(0)"
        : "=&v"(t0), "=&v"(t1), "=&v"(t2), "=&v"(t3), "=&v"(t4), "=&v"(t5),
          "=&v"(t6), "=&v"(t7), "=&v"(t8), "=&v"(t9), "=&v"(t10), "=&v"(t11),
          "=&v"(t12), "=&v"(t13), "=&v"(t14), "=&v"(t15), "=&v"(t16), "=&v"(t17)
        : "v"(off[0]), "v"(off[1]), "v"(off[2]), "v"(off[3]), "v"(off[4]),
          "v"(off[5]), "v"(off[6]), "v"(off[7]), "v"(off[8]), "s"(px));

    u32x4 xr[18] = {t0, t1, t2, t3, t4, t5, t6, t7, t8, t9,
                    t10, t11, t12, t13, t14, t15, t16, t17};
    // Zero OOB taps; corr table removes the residual popc(w) garbage.
#pragma unroll
    for (int k = 0; k < 9; ++k) {
        u32x4 mv = {vm[k], vm[k], vm[k], vm[k]};
        xr[2 * k]     &= mv;
        xr[2 * k + 1] &= mv;
    }

    __syncthreads();   // corr table staged

    int base = nv << 8;                     // 256 * valid taps
    float aw = alpha[w];                    // faithful broadcast: alpha[WIDTH]
    int ht  = (h == 0) ? 0 : ((h == HH - 1) ? 2 : 1);
    int wtp = (w == 0) ? 0 : ((w == WW - 1) ? 2 : 1);
    const u16* corrP = &corrs[(ht * 3 + wtp) * COUT];
    const u32* pwu = reinterpret_cast<const u32*>(pw);
    float* op = out + (size_t)n * COUT * HH * WW + (size_t)h * WW + w;

#pragma unroll 1
    for (int co = 0; co < COUT; ++co) {
        // Uniform address: compiler scalarizes to s_load_dwordx16 (SGPR
        // weights; v_xor takes the s-operand directly -- zero LDS, zero
        // extra VALU).
        const u32x4* wp = reinterpret_cast<const u32x4*>(pwu + co * 72);
        int M = 0;
#pragma unroll
        for (int j = 0; j < 18; ++j) {
            u32x4 v = xr[j] ^ wp[j];
            M += __popc(v.x) + __popc(v.y) + __popc(v.z) + __popc(v.w);
        }
        M -= (int)corrP[co];
        op[(size_t)co * (HH * WW)] = (float)(base - 2 * M) * aw;
    }
}

extern "C" void kernel_launch(void* const* d_in, const int* in_sizes, int n_in,
                              void* d_out, int out_size, void* d_ws, size_t ws_size,
                              hipStream_t stream) {
    const float* x  = (const float*)d_in[0];
    const float* wt = (const float*)d_in[1];
    float* out = (float*)d_out;

    char* ws = (char*)d_ws;
    const size_t PX_BYTES   = (size_t)NIMG * HH * WW * 4 * sizeof(u64);  // 8 MiB
    const size_t PW_BYTES   = (size_t)COUT * 36 * sizeof(u64);           // 36 KiB
    const size_t AL_BYTES   = 512;
    const size_t CORR_BYTES = (size_t)9 * COUT * sizeof(u16);            // 2.25 KiB
    if (ws_size < PX_BYTES + PW_BYTES + AL_BYTES + CORR_BYTES) return;
    u64*   px    = (u64*)ws;
    u64*   pw    = (u64*)(ws + PX_BYTES);
    float* alpha = (float*)(ws + PX_BYTES + PW_BYTES);
    u16*   corrg = (u16*)(ws + PX_BYTES + PW_BYTES + AL_BYTES);

    pack_x_kernel<<<NIMG * HH * WW / 256, 256, 0, stream>>>(x, px);
    pack_w_kernel<<<COUT, 256, 0, stream>>>(wt, pw, alpha, corrg);
    conv_kernel<<<NIMG * (HH / 2), 256, 0, stream>>>(px, pw, alpha, corrg, out);
}

// Round 7
// 250.752 us; speedup vs baseline: 1.0856x; 1.0856x over previous
//
#include <hip/hip_runtime.h>
#include <stdint.h>

#define CIN   256
#define COUT  128
#define HH    128
#define WW    128
#define NIMG  16

typedef unsigned long long u64;
typedef unsigned int u32;
typedef unsigned short u16;
typedef u32 u32x4 __attribute__((ext_vector_type(4)));

// ---------------------------------------------------------------------------
// Pack sign bits of x: px[(n*HH + h)*WW + w][word 0..3], bit (c&63) of word
// (c>>6) is (x[n][c][h][w] > 0). Position-major, 4 u64 (32 B) per position.
// ---------------------------------------------------------------------------
__global__ __launch_bounds__(256) void pack_x_kernel(const float* __restrict__ x,
                                                     u64* __restrict__ px) {
    int t = blockIdx.x * 256 + threadIdx.x;
    int w = t & (WW - 1);
    int h = (t >> 7) & (HH - 1);
    int n = t >> 14;
    const float* xp = x + (size_t)n * CIN * HH * WW + (size_t)h * WW + w;
    u64 words[4];
#pragma unroll
    for (int wd = 0; wd < 4; ++wd) {
        u64 acc = 0;
#pragma unroll 16
        for (int cc = 0; cc < 64; ++cc) {
            float v = xp[(size_t)(wd * 64 + cc) * (HH * WW)];
            acc |= (u64)(v > 0.0f) << cc;
        }
        words[wd] = acc;
    }
    ulonglong2* o = reinterpret_cast<ulonglong2*>(px + (size_t)t * 4);
    o[0] = make_ulonglong2(words[0], words[1]);
    o[1] = make_ulonglong2(words[2], words[3]);
}

// ---------------------------------------------------------------------------
// Pack weight sign bits, alpha, and full-channel border-correction table.
// pw[co*36 + k*4 + word] (u64). corrg[pat*COUT + co] (u16) = sum over taps
// invalid in border pattern `pat` of popcount(w[co][tap]) over 256 channels.
// pat = ht*3+wt, ht/wt in {0=low border, 1=interior, 2=high border}.
// ---------------------------------------------------------------------------
__global__ __launch_bounds__(256) void pack_w_kernel(const float* __restrict__ wt,
                                                     u64* __restrict__ pw,
                                                     float* __restrict__ alpha,
                                                     u16* __restrict__ corrg) {
    int co = blockIdx.x;
    int c  = threadIdx.x;        // 0..255 = input channel
    int lane = c & 63;
    int word = c >> 6;
    __shared__ u64 wsh[9][4];
    __shared__ u32 pct[9];
    __shared__ float red[4];
    const float* wp = wt + ((size_t)co * CIN + c) * 9;
    float vals[9];
    float asum = 0.0f;
#pragma unroll
    for (int k = 0; k < 9; ++k) { vals[k] = wp[k]; asum += fabsf(vals[k]); }
#pragma unroll
    for (int k = 0; k < 9; ++k) {
        u64 m = __ballot(vals[k] > 0.0f);
        if (lane == 0) { pw[co * 36 + k * 4 + word] = m; wsh[k][word] = m; }
    }
    for (int off = 32; off > 0; off >>= 1) asum += __shfl_down(asum, off);
    if (lane == 0) red[word] = asum;
    __syncthreads();
    if (c < 9)
        pct[c] = __popcll(wsh[c][0]) + __popcll(wsh[c][1]) +
                 __popcll(wsh[c][2]) + __popcll(wsh[c][3]);
    if (c == 0) alpha[co] = (red[0] + red[1] + red[2] + red[3]) * (1.0f / 2304.0f);
    __syncthreads();
    if (c < 9) {
        int pat = c, ht = pat / 3, wtp = pat % 3;
        u32 corr = 0;
#pragma unroll
        for (int k = 0; k < 9; ++k) {
            int dh = k / 3 - 1, dw = k % 3 - 1;
            bool inv = (dh == -1 && ht == 0) || (dh == 1 && ht == 2) ||
                       (dw == -1 && wtp == 0) || (dw == 1 && wtp == 2);
            if (inv) corr += pct[k];
        }
        corrg[pat * COUT + co] = (u16)corr;
    }
}

// ---------------------------------------------------------------------------
// XNOR conv v7 -- register-tiled bit-GEMM (v6 + tap-offset fix).
// v6 bug: LDS col of position p is p+1 (col 0 = left halo), so tap dw=-1
// for position w0+8i reads byte (w0+8i)*32 = xrow + i*256; v6 started the
// dw walk at xrow+32 (center tap) -> conv shifted one pixel left, absmax
// 304. Fix: xc starts at xrow.
// Design: each thread computes an 8x8 (position x co) tile, so every 16B
// LDS read feeds 8 outputs. Per 16B K-chunk: 8 x-reads + 8 w-reads + 512
// VALU -> LDS pipe ~19% of VALU time (R1-R5 were 100% LDS/broadcast-bound
// at ~215us). Block = row h, all 128 co; x rows h-1..h+1 (zero halo) +
// weights + corr/alpha staged once. Interleaved tiles (w0+8i, c0+8j) keep
// LDS reads at <=2-way bank aliasing (free, m136). Borders: zeros in LDS +
// per-pattern corr subtraction; hot loop has ZERO masks.
// out[n][co][h][w] = (256*nv - 2*mismatch) * alpha[w]   (alpha by WIDTH!)
// ---------------------------------------------------------------------------
__global__ __launch_bounds__(256, 3) void conv_kernel(const u64* __restrict__ px,
                                                      const u64* __restrict__ pw,
                                                      const float* __restrict__ alpha,
                                                      const u16* __restrict__ corrg,
                                                      float* __restrict__ out) {
    __shared__ __align__(16) u32 xlds[3 * 130 * 8];   // 12480 B: 3 rows x 130 cols x 32B
    __shared__ __align__(16) u32 wlds[COUT * 72];     // 36864 B: 128 co x 288B
    __shared__ u16 corrs[9 * COUT];                   // 2304 B
    __shared__ float alds[COUT];                      // 512 B (alpha indexed by w; WW==COUT)

    int tid = threadIdx.x;
    int bid = blockIdx.x;                 // n*128 + h
    int h = bid & (HH - 1);
    int n = bid >> 7;

    // ---- stage weights (36864B = 2304 u32x4) ----
    {
        const u32x4* s = reinterpret_cast<const u32x4*>(pw);
        u32x4* d = reinterpret_cast<u32x4*>(wlds);
        for (int i = tid; i < 2304; i += 256) d[i] = s[i];
    }
    // ---- stage corr (576 u32) + alpha ----
    {
        const u32* cs = reinterpret_cast<const u32*>(corrg);
        u32* cd = reinterpret_cast<u32*>(corrs);
        for (int i = tid; i < 576; i += 256) cd[i] = cs[i];
        if (tid < COUT) alds[tid] = alpha[tid];
    }
    // ---- stage x rows h-1..h+1, zero halo (cols 0 and 129, missing rows) ----
    {
        u32x4* xd = reinterpret_cast<u32x4*>(xlds);   // 260 u32x4 per row
#pragma unroll
        for (int r = 0; r < 3; ++r) {
            int gh = h - 1 + r;
            u32x4 v = {0, 0, 0, 0};
            if (gh >= 0 && gh < HH) {
                const u32x4* xs = reinterpret_cast<const u32x4*>(
                    px + ((size_t)(n * HH + gh) * WW) * 4);
                v = xs[tid];                        // position tid>>1, piece tid&1
            }
            xd[r * 260 + 2 + tid] = v;              // position p -> col p+1
            if (tid < 4) {
                u32x4 z = {0, 0, 0, 0};
                xd[r * 260 + (tid >> 1) * 258 + (tid & 1)] = z;  // cols 0,129
            }
        }
    }
    __syncthreads();

    int lane = tid & 63;
    int wave = tid >> 6;
    int wp = wave & 1, wc = wave >> 1;
    int pm = lane & 7, cn = lane >> 3;
    int w0 = wp * 64 + pm;       // thread positions: w0 + 8i
    int c0 = wc * 64 + cn;       // thread co:        c0 + 8j

    int acc[8][8];
#pragma unroll
    for (int i = 0; i < 8; ++i)
#pragma unroll
        for (int j = 0; j < 8; ++j) acc[i][j] = 0;

    // K-loop: 9 taps x 2 halves (16B each).
    //  x: tap dw (0..2 == -1..+1) for position w0+8i -> col w0+8i+dw
    //     -> byte (w0+8i+dw)*32  (col = position+1 absorbs the -1)
    //  w: co c0+8j, tap k -> byte (c0+8j)*288 + k*32
    const char* xrow = reinterpret_cast<const char*>(xlds) + w0 * 32;
    const char* wtap = reinterpret_cast<const char*>(wlds) + c0 * 288;
#pragma unroll 1
    for (int dh = 0; dh < 3; ++dh) {
        const char* xc = xrow;                 // dw=-1 tap: col w0+8i  [v6 fix]
#pragma unroll 1
        for (int dw = 0; dw < 3; ++dw) {
            const char* xh = xc;
            const char* wh = wtap;
#pragma unroll 1
            for (int half = 0; half < 2; ++half) {
                u32x4 xa[8], wb[8];
#pragma unroll
                for (int i = 0; i < 8; ++i)
                    xa[i] = *reinterpret_cast<const u32x4*>(xh + i * 256);
#pragma unroll
                for (int j = 0; j < 8; ++j)
                    wb[j] = *reinterpret_cast<const u32x4*>(wh + j * 2304);
#pragma unroll
                for (int i = 0; i < 8; ++i)
#pragma unroll
                    for (int j = 0; j < 8; ++j) {
                        u32x4 v = xa[i] ^ wb[j];
                        acc[i][j] += __popc(v.x) + __popc(v.y) +
                                     __popc(v.z) + __popc(v.w);
                    }
                xh += 16;
                wh += 16;
            }
            xc += 32;
            wtap += 32;
        }
        xrow += 130 * 32;
    }

    // ---- epilogue: corr subtract, scale, store ----
    int hlow = (h == 0), hhigh = (h == HH - 1);
    int hpat = hlow ? 0 : (hhigh ? 2 : 1);
    int rowsv = 3 - hlow - hhigh;
    float* outb = out + (size_t)n * COUT * HH * WW + (size_t)h * WW;
#pragma unroll
    for (int i = 0; i < 8; ++i) {
        int w = w0 + 8 * i;
        int wlow = (w == 0), whigh = (w == WW - 1);
        int wpat = wlow ? 0 : (whigh ? 2 : 1);
        int base = (rowsv * (3 - wlow - whigh)) << 8;
        float aw = alds[w];                       // alpha by WIDTH (faithful)
        const u16* cp = &corrs[(hpat * 3 + wpat) * COUT + c0];
#pragma unroll
        for (int j = 0; j < 8; ++j) {
            int M = acc[i][j] - (int)cp[8 * j];
            outb[(size_t)(c0 + 8 * j) * (HH * WW) + w] =
                (float)(base - 2 * M) * aw;
        }
    }
}

extern "C" void kernel_launch(void* const* d_in, const int* in_sizes, int n_in,
                              void* d_out, int out_size, void* d_ws, size_t ws_size,
                              hipStream_t stream) {
    const float* x  = (const float*)d_in[0];
    const float* wt = (const float*)d_in[1];
    float* out = (float*)d_out;

    char* ws = (char*)d_ws;
    const size_t PX_BYTES   = (size_t)NIMG * HH * WW * 4 * sizeof(u64);  // 8 MiB
    const size_t PW_BYTES   = (size_t)COUT * 36 * sizeof(u64);           // 36 KiB
    const size_t AL_BYTES   = 512;
    const size_t CORR_BYTES = (size_t)9 * COUT * sizeof(u16);            // 2.25 KiB
    if (ws_size < PX_BYTES + PW_BYTES + AL_BYTES + CORR_BYTES) return;
    u64*   px    = (u64*)ws;
    u64*   pw    = (u64*)(ws + PX_BYTES);
    float* alpha = (float*)(ws + PX_BYTES + PW_BYTES);
    u16*   corrg = (u16*)(ws + PX_BYTES + PW_BYTES + AL_BYTES);

    pack_x_kernel<<<NIMG * HH * WW / 256, 256, 0, stream>>>(x, px);
    pack_w_kernel<<<COUT, 256, 0, stream>>>(wt, pw, alpha, corrg);
    conv_kernel<<<NIMG * HH, 256, 0, stream>>>(px, pw, alpha, corrg, out);
}

// Round 8
// 244.196 us; speedup vs baseline: 1.1147x; 1.0268x over previous
//
#include <hip/hip_runtime.h>
#include <stdint.h>

#define CIN   256
#define COUT  128
#define HH    128
#define WW    128
#define NIMG  16

typedef unsigned long long u64;
typedef unsigned int u32;
typedef unsigned short u16;
typedef u32 u32x4 __attribute__((ext_vector_type(4)));

// ---------------------------------------------------------------------------
// Pack sign bits of x: px[(n*HH + h)*WW + w][word 0..3], bit (c&63) of word
// (c>>6) is (x[n][c][h][w] > 0). Position-major, 4 u64 (32 B) per position.
// ---------------------------------------------------------------------------
__global__ __launch_bounds__(256) void pack_x_kernel(const float* __restrict__ x,
                                                     u64* __restrict__ px) {
    int t = blockIdx.x * 256 + threadIdx.x;
    int w = t & (WW - 1);
    int h = (t >> 7) & (HH - 1);
    int n = t >> 14;
    const float* xp = x + (size_t)n * CIN * HH * WW + (size_t)h * WW + w;
    u64 words[4];
#pragma unroll
    for (int wd = 0; wd < 4; ++wd) {
        u64 acc = 0;
#pragma unroll 16
        for (int cc = 0; cc < 64; ++cc) {
            float v = xp[(size_t)(wd * 64 + cc) * (HH * WW)];
            acc |= (u64)(v > 0.0f) << cc;
        }
        words[wd] = acc;
    }
    ulonglong2* o = reinterpret_cast<ulonglong2*>(px + (size_t)t * 4);
    o[0] = make_ulonglong2(words[0], words[1]);
    o[1] = make_ulonglong2(words[2], words[3]);
}

// ---------------------------------------------------------------------------
// Pack weight sign bits, alpha, and full-channel border-correction table.
// pw[co*36 + k*4 + word] (u64). corrg[pat*COUT + co] (u16) = sum over taps
// invalid in border pattern `pat` of popcount(w[co][tap]) over 256 channels.
// pat = ht*3+wt, ht/wt in {0=low border, 1=interior, 2=high border}.
// ---------------------------------------------------------------------------
__global__ __launch_bounds__(256) void pack_w_kernel(const float* __restrict__ wt,
                                                     u64* __restrict__ pw,
                                                     float* __restrict__ alpha,
                                                     u16* __restrict__ corrg) {
    int co = blockIdx.x;
    int c  = threadIdx.x;        // 0..255 = input channel
    int lane = c & 63;
    int word = c >> 6;
    __shared__ u64 wsh[9][4];
    __shared__ u32 pct[9];
    __shared__ float red[4];
    const float* wp = wt + ((size_t)co * CIN + c) * 9;
    float vals[9];
    float asum = 0.0f;
#pragma unroll
    for (int k = 0; k < 9; ++k) { vals[k] = wp[k]; asum += fabsf(vals[k]); }
#pragma unroll
    for (int k = 0; k < 9; ++k) {
        u64 m = __ballot(vals[k] > 0.0f);
        if (lane == 0) { pw[co * 36 + k * 4 + word] = m; wsh[k][word] = m; }
    }
    for (int off = 32; off > 0; off >>= 1) asum += __shfl_down(asum, off);
    if (lane == 0) red[word] = asum;
    __syncthreads();
    if (c < 9)
        pct[c] = __popcll(wsh[c][0]) + __popcll(wsh[c][1]) +
                 __popcll(wsh[c][2]) + __popcll(wsh[c][3]);
    if (c == 0) alpha[co] = (red[0] + red[1] + red[2] + red[3]) * (1.0f / 2304.0f);
    __syncthreads();
    if (c < 9) {
        int pat = c, ht = pat / 3, wtp = pat % 3;
        u32 corr = 0;
#pragma unroll
        for (int k = 0; k < 9; ++k) {
            int dh = k / 3 - 1, dw = k % 3 - 1;
            bool inv = (dh == -1 && ht == 0) || (dh == 1 && ht == 2) ||
                       (dw == -1 && wtp == 0) || (dw == 1 && wtp == 2);
            if (inv) corr += pct[k];
        }
        corrg[pat * COUT + co] = (u16)corr;
    }
}

// ---------------------------------------------------------------------------
// XNOR conv v8 -- 8x4 register tile, 512-thread blocks (diagnostic round).
// R7 (8x8 tile, 256t): 196us @ VALUBusy 85.7%, VGPR_Count=72 => acc[8][8]
// was AGPR-parked (needs >=128 arch VGPRs). Backsolving the busy cycles:
// ~50k cyc/wave vs 18.4k static @2cyc. Fits either AGPR round-trips or
// v_bcnt at quarter rate (4608 xor x2 + 4608 bcnt x8 + overhead ~= 49k).
// This version eliminates the pressure explanation: 8 pos x 4 co per
// thread (acc 32 + xa 32 + wb 16 ~= 95 VGPR < 128 cap), 512 threads,
// occupancy 12->16 waves/CU. Same total VALU work, same LDS reuse (16B
// read feeds >=4 outputs), <=2-way bank aliasing (8-lane broadcasts).
// If dur ~75us: R7 was pressure; if ~150us: bcnt is quarter-rate -> MFMA.
// out[n][co][h][w] = (256*nv - 2*mismatch) * alpha[w]   (alpha by WIDTH!)
// ---------------------------------------------------------------------------
__global__ __launch_bounds__(512, 4) void conv_kernel(const u64* __restrict__ px,
                                                      const u64* __restrict__ pw,
                                                      const float* __restrict__ alpha,
                                                      const u16* __restrict__ corrg,
                                                      float* __restrict__ out) {
    __shared__ __align__(16) u32 xlds[3 * 130 * 8];   // 12480 B
    __shared__ __align__(16) u32 wlds[COUT * 72];     // 36864 B
    __shared__ u16 corrs[9 * COUT];                   // 2304 B
    __shared__ float alds[WW];                        // 512 B

    int tid = threadIdx.x;
    int bid = blockIdx.x;                 // n*128 + h
    int h = bid & (HH - 1);
    int n = bid >> 7;

    // ---- stage weights (2304 u32x4) ----
    {
        const u32x4* s = reinterpret_cast<const u32x4*>(pw);
        u32x4* d = reinterpret_cast<u32x4*>(wlds);
        for (int i = tid; i < 2304; i += 512) d[i] = s[i];
    }
    // ---- stage corr (576 u32) + alpha ----
    {
        const u32* cs = reinterpret_cast<const u32*>(corrg);
        u32* cd = reinterpret_cast<u32*>(corrs);
        for (int i = tid; i < 576; i += 512) cd[i] = cs[i];
        if (tid < WW) alds[tid] = alpha[tid];
    }
    // ---- stage x rows h-1..h+1 (260 u32x4/row; pos p -> col p+1; halo=0) ----
    {
        u32x4* xd = reinterpret_cast<u32x4*>(xlds);
#pragma unroll
        for (int r = 0; r < 3; ++r) {
            int gh = h - 1 + r;
            if (tid < 256) {
                u32x4 v = {0, 0, 0, 0};
                if (gh >= 0 && gh < HH) {
                    const u32x4* xs = reinterpret_cast<const u32x4*>(
                        px + ((size_t)(n * HH + gh) * WW) * 4);
                    v = xs[tid];
                }
                xd[r * 260 + 2 + tid] = v;
            } else if (tid < 260) {
                int t = tid - 256;
                u32x4 z = {0, 0, 0, 0};
                xd[r * 260 + (t >> 1) * 258 + (t & 1)] = z;   // cols 0,129
            }
        }
    }
    __syncthreads();

    int lane = tid & 63;
    int wave = tid >> 6;                       // 0..7
    int p0 = lane & 7;
    int c0 = ((wave & 3) << 3) | (lane >> 3);  // 0..31
    int ph = wave >> 2;                        // position half
    int w0 = ph * 64 + p0;                     // positions w0 + 8i, i<8
                                               // co = c0 + 32j, j<4

    int acc[8][4];
#pragma unroll
    for (int i = 0; i < 8; ++i)
#pragma unroll
        for (int j = 0; j < 4; ++j) acc[i][j] = 0;

    const char* xrow  = reinterpret_cast<const char*>(xlds) + w0 * 32;
    const char* wbase = reinterpret_cast<const char*>(wlds) + c0 * 288;

#pragma unroll 1
    for (int dh = 0; dh < 3; ++dh) {
#pragma unroll
        for (int dw = 0; dw < 3; ++dw) {
            const char* xc = xrow + dh * (130 * 32) + dw * 32;  // tap dw=-1..+1
            const char* wh = wbase + (dh * 3 + dw) * 32;
#pragma unroll
            for (int hb = 0; hb < 2; ++hb) {
                u32x4 xa[8], wb[4];
#pragma unroll
                for (int i = 0; i < 8; ++i)
                    xa[i] = *reinterpret_cast<const u32x4*>(xc + i * 256 + hb * 16);
#pragma unroll
                for (int j = 0; j < 4; ++j)
                    wb[j] = *reinterpret_cast<const u32x4*>(wh + j * 9216 + hb * 16);
#pragma unroll
                for (int i = 0; i < 8; ++i)
#pragma unroll
                    for (int j = 0; j < 4; ++j) {
                        u32x4 v = xa[i] ^ wb[j];
                        acc[i][j] += __popc(v.x) + __popc(v.y) +
                                     __popc(v.z) + __popc(v.w);
                    }
            }
        }
    }

    // ---- epilogue: corr subtract, scale, store ----
    int hlow = (h == 0), hhigh = (h == HH - 1);
    int hpat = hlow ? 0 : (hhigh ? 2 : 1);
    int rowsv = 3 - hlow - hhigh;
    float* outb = out + (size_t)n * COUT * HH * WW + (size_t)h * WW;
#pragma unroll
    for (int i = 0; i < 8; ++i) {
        int w = w0 + 8 * i;
        int wlow = (w == 0), whigh = (w == WW - 1);
        int wpat = wlow ? 0 : (whigh ? 2 : 1);
        int base = (rowsv * (3 - wlow - whigh)) << 8;
        float aw = alds[w];                       // alpha by WIDTH (faithful)
        const u16* cp = &corrs[(hpat * 3 + wpat) * COUT];
#pragma unroll
        for (int j = 0; j < 4; ++j) {
            int co = c0 + 32 * j;
            int M = acc[i][j] - (int)cp[co];
            outb[(size_t)co * (HH * WW) + w] = (float)(base - 2 * M) * aw;
        }
    }
}

extern "C" void kernel_launch(void* const* d_in, const int* in_sizes, int n_in,
                              void* d_out, int out_size, void* d_ws, size_t ws_size,
                              hipStream_t stream) {
    const float* x  = (const float*)d_in[0];
    const float* wt = (const float*)d_in[1];
    float* out = (float*)d_out;

    char* ws = (char*)d_ws;
    const size_t PX_BYTES   = (size_t)NIMG * HH * WW * 4 * sizeof(u64);  // 8 MiB
    const size_t PW_BYTES   = (size_t)COUT * 36 * sizeof(u64);           // 36 KiB
    const size_t AL_BYTES   = 512;
    const size_t CORR_BYTES = (size_t)9 * COUT * sizeof(u16);            // 2.25 KiB
    if (ws_size < PX_BYTES + PW_BYTES + AL_BYTES + CORR_BYTES) return;
    u64*   px    = (u64*)ws;
    u64*   pw    = (u64*)(ws + PX_BYTES);
    float* alpha = (float*)(ws + PX_BYTES + PW_BYTES);
    u16*   corrg = (u16*)(ws + PX_BYTES + PW_BYTES + AL_BYTES);

    pack_x_kernel<<<NIMG * HH * WW / 256, 256, 0, stream>>>(x, px);
    pack_w_kernel<<<COUT, 256, 0, stream>>>(wt, pw, alpha, corrg);
    conv_kernel<<<NIMG * HH, 512, 0, stream>>>(px, pw, alpha, corrg, out);
}

// Round 9
// 193.173 us; speedup vs baseline: 1.4092x; 1.2641x over previous
//
#include <hip/hip_runtime.h>
#include <stdint.h>

#define CIN   256
#define COUT  128
#define HH    128
#define WW    128
#define NIMG  16

typedef unsigned long long u64;
typedef unsigned int u32;
typedef u32 u32x2 __attribute__((ext_vector_type(2)));
typedef u32 u32x4 __attribute__((ext_vector_type(4)));
typedef int i32x4 __attribute__((ext_vector_type(4)));
typedef int i32x16 __attribute__((ext_vector_type(16)));
typedef signed char i8;

// ---------------------------------------------------------------------------
// Pack sign bits of x: px[(n*HH+h)*WW + w][word 0..3]; bit (c&63) of word
// (c>>6) = (x[n][c][h][w] > 0). 32 B per position. 8 MiB total (ws-proven).
// ---------------------------------------------------------------------------
__global__ __launch_bounds__(256) void pack_x_kernel(const float* __restrict__ x,
                                                     u64* __restrict__ px) {
    int t = blockIdx.x * 256 + threadIdx.x;
    int w = t & (WW - 1);
    int h = (t >> 7) & (HH - 1);
    int n = t >> 14;
    const float* xp = x + (size_t)n * CIN * HH * WW + (size_t)h * WW + w;
    u64 words[4];
#pragma unroll
    for (int wd = 0; wd < 4; ++wd) {
        u64 acc = 0;
#pragma unroll 16
        for (int cc = 0; cc < 64; ++cc) {
            float v = xp[(size_t)(wd * 64 + cc) * (HH * WW)];
            acc |= (u64)(v > 0.0f) << cc;
        }
        words[wd] = acc;
    }
    ulonglong2* o = reinterpret_cast<ulonglong2*>(px + (size_t)t * 4);
    o[0] = make_ulonglong2(words[0], words[1]);
    o[1] = make_ulonglong2(words[2], words[3]);
}

// ---------------------------------------------------------------------------
// Weights to i8 +-1, K-major per co: wb[co*2304 + tap*256 + c]; alpha[co].
// ---------------------------------------------------------------------------
__global__ __launch_bounds__(256) void pack_w_kernel(const float* __restrict__ wt,
                                                     i8* __restrict__ wb,
                                                     float* __restrict__ alpha) {
    int co = blockIdx.x;
    int c  = threadIdx.x;        // input channel
    int lane = c & 63;
    int word = c >> 6;
    const float* wp = wt + ((size_t)co * CIN + c) * 9;
    float asum = 0.0f;
#pragma unroll
    for (int k = 0; k < 9; ++k) {
        float v = wp[k];
        asum += fabsf(v);
        wb[(size_t)co * 2304 + k * 256 + c] = (v > 0.0f) ? (i8)1 : (i8)-1;
    }
    __shared__ float red[4];
    for (int off = 32; off > 0; off >>= 1) asum += __shfl_down(asum, off);
    if (lane == 0) red[word] = asum;
    __syncthreads();
    if (c == 0) alpha[co] = (red[0] + red[1] + red[2] + red[3]) * (1.0f / 2304.0f);
}

// ---------------------------------------------------------------------------
// XNOR conv v9 -- i8 MFMA implicit GEMM.
// R7/R8 forensics: popcount path is VALU-roofline-bound (~200us) because
// v_bcnt runs at ~quarter rate (both rounds fit 2.7x static@2cyc exactly).
// Switch to the matrix pipe: C[co][pos] = sum_k W[co][k]*X[pos][k], K=2304
// (tap-major), i8 +-1 operands, mfma_i32_32x32x32_i8 (4404 TOPS -> ~35us
// floor). Zero-padding = zero i8 bytes -> exact conv semantics, no corr.
// Block=(n,h): X = 3 rows x 130 pos x 256 i8 in LDS, expanded in-kernel
// from bit-packed px (nibble mul-spread + v_perm); W streams via 2x16KiB
// double-buffered LDS chunks (chunk = half-tap of K). XOR swizzles:
// X 16B-granule (col&15)<<4 on b128 reads; W 8B-granule (co&15)<<3 on b64
// pairs -> <=2-way banks. 8 waves, wave tile 64co x 32pos (acc 2x16).
// C layout (HW-verified, dtype-indep): col=lane&31=pos -> coalesced store.
// out[n][co][h][w] = (float)acc * alpha[w]   (alpha by WIDTH!)
// ---------------------------------------------------------------------------
__global__ __launch_bounds__(512, 2) void conv_kernel(const u64* __restrict__ px,
                                                      const i8* __restrict__ wb,
                                                      const float* __restrict__ alpha,
                                                      float* __restrict__ out) {
    __shared__ __align__(16) i8 xl[3 * 130 * 256];    // 99840 B, swizzled
    __shared__ __align__(16) i8 wl[2][128 * 128];     // 32768 B, swizzled
    __shared__ float alds[WW];                        // 512 B

    int tid = threadIdx.x;
    int bid = blockIdx.x;                 // n*128 + h
    int h = bid & (HH - 1);
    int n = bid >> 7;

    if (tid < WW) alds[tid] = alpha[tid];

    // ---- W chunk 0: issue global loads early ----
    int sco = tid >> 2, sq = tid & 3;     // 128 co x 4 quarters
    const u32x4* wsrc0 = reinterpret_cast<const u32x4*>(
        wb + (size_t)sco * 2304 + 0 * 128 + sq * 32);
    u32x4 g0 = wsrc0[0], g1 = wsrc0[1];

    // ---- X stage: expand bit-packed px -> i8 rows, zero halo, swizzled ----
    if (tid < 390) {
        int r = (tid >= 260) ? 2 : ((tid >= 130) ? 1 : 0);
        int p = tid - r * 130;            // col 0..129; position w = p-1
        int gh = h - 1 + r;
        i8* dst = xl + (r * 130 + p) * 256;
        int swz = (p & 15) << 4;
        bool valid = (p >= 1) && (p <= 128) && (gh >= 0) && (gh < HH);
        if (valid) {
            const u32x4* s = reinterpret_cast<const u32x4*>(
                px + (size_t)((n * HH + gh) * WW + (p - 1)) * 4);
            u32x4 a = s[0], b = s[1];
            u32 bw[8] = {a.x, a.y, a.z, a.w, b.x, b.y, b.z, b.w};
#pragma unroll
            for (int i = 0; i < 16; ++i) {
                u32 o[4];
#pragma unroll
                for (int jj = 0; jj < 4; ++jj) {
                    int j = 4 * i + jj;
                    u32 nib = (bw[j >> 3] >> ((j & 7) * 4)) & 0xFu;
                    u32 spread = (nib * 0x00204081u) & 0x01010101u;
                    // byte: bit=1 -> 0x01 (sel 4 -> arg0), bit=0 -> 0xFF (sel 0 -> arg1)
                    o[jj] = __builtin_amdgcn_perm(0x01010101u, 0xFFFFFFFFu, spread << 2);
                }
                u32x4 v = {o[0], o[1], o[2], o[3]};
                *reinterpret_cast<u32x4*>(dst + ((i * 16) ^ swz)) = v;
            }
        } else {
            u32x4 z = {0, 0, 0, 0};
#pragma unroll
            for (int i = 0; i < 16; ++i)
                *reinterpret_cast<u32x4*>(dst + ((i * 16) ^ swz)) = z;
        }
    }

    // ---- write W chunk 0 (swizzled 8B granule) ----
    {
        i8* basew = wl[0] + (sco << 7);
        int swzc = (sco & 15) << 3;
        int qo = sq * 32;
        u32x2 p0 = {g0.x, g0.y}, p1 = {g0.z, g0.w};
        u32x2 p2 = {g1.x, g1.y}, p3 = {g1.z, g1.w};
        *reinterpret_cast<u32x2*>(basew + ((qo + 0)  ^ swzc)) = p0;
        *reinterpret_cast<u32x2*>(basew + ((qo + 8)  ^ swzc)) = p1;
        *reinterpret_cast<u32x2*>(basew + ((qo + 16) ^ swzc)) = p2;
        *reinterpret_cast<u32x2*>(basew + ((qo + 24) ^ swzc)) = p3;
    }
    __syncthreads();

    // ---- main K loop: 18 chunks (chunk = 128 k = half tap), 4 MFMA steps ----
    int lane = tid & 63;
    int wave = tid >> 6;
    int l31 = lane & 31;
    int hi  = lane >> 5;
    int pos0 = (wave >> 1) * 32;          // 4 position groups
    int co0  = (wave & 1) * 64;           // 2 co groups (2 sub-tiles of 32)

    i32x16 acc0 = {0,0,0,0,0,0,0,0,0,0,0,0,0,0,0,0};
    i32x16 acc1 = {0,0,0,0,0,0,0,0,0,0,0,0,0,0,0,0};

    int swzw = (l31 & 15) << 3;

#pragma unroll 1
    for (int ch = 0; ch < 18; ++ch) {
        int nxt = ch + 1;
        if (nxt < 18) {                   // prefetch next W chunk to regs
            const u32x4* ws = reinterpret_cast<const u32x4*>(
                wb + (size_t)sco * 2304 + nxt * 128 + sq * 32);
            g0 = ws[0]; g1 = ws[1];
        }
        int tap = ch >> 1;
        int c0w = (ch & 1) << 7;          // channel-offset within tap
        int r   = tap / 3;
        int dwi = tap - r * 3;            // 0..2 == dw -1..+1 (col absorbs)
        int col = pos0 + l31 + dwi;
        const i8* xbase = xl + ((r * 130 + col) << 8);
        int swzx = (col & 15) << 4;
        const i8* wbuf = wl[ch & 1];
        const i8* wb0 = wbuf + ((co0 + l31) << 7);
        const i8* wb1 = wbuf + ((co0 + 32 + l31) << 7);
#pragma unroll
        for (int ks = 0; ks < 4; ++ks) {
            int kk = ks * 32 + hi * 16;
            u32x4 xf = *reinterpret_cast<const u32x4*>(xbase + ((c0w + kk) ^ swzx));
            u32x2 wa0 = *reinterpret_cast<const u32x2*>(wb0 + (kk ^ swzw));
            u32x2 wa1 = *reinterpret_cast<const u32x2*>(wb0 + ((kk + 8) ^ swzw));
            u32x2 wc0 = *reinterpret_cast<const u32x2*>(wb1 + (kk ^ swzw));
            u32x2 wc1 = *reinterpret_cast<const u32x2*>(wb1 + ((kk + 8) ^ swzw));
            i32x4 wf0 = {(int)wa0.x, (int)wa0.y, (int)wa1.x, (int)wa1.y};
            i32x4 wf1 = {(int)wc0.x, (int)wc0.y, (int)wc1.x, (int)wc1.y};
            i32x4 xfi = {(int)xf.x, (int)xf.y, (int)xf.z, (int)xf.w};
            acc0 = __builtin_amdgcn_mfma_i32_32x32x32_i8(wf0, xfi, acc0, 0, 0, 0);
            acc1 = __builtin_amdgcn_mfma_i32_32x32x32_i8(wf1, xfi, acc1, 0, 0, 0);
        }
        __syncthreads();                  // all reads of wl[nxt&1] (chunk ch-1) done
        if (nxt < 18) {
            i8* basew = wl[nxt & 1] + (sco << 7);
            int swzc = (sco & 15) << 3;
            int qo = sq * 32;
            u32x2 p0 = {g0.x, g0.y}, p1 = {g0.z, g0.w};
            u32x2 p2 = {g1.x, g1.y}, p3 = {g1.z, g1.w};
            *reinterpret_cast<u32x2*>(basew + ((qo + 0)  ^ swzc)) = p0;
            *reinterpret_cast<u32x2*>(basew + ((qo + 8)  ^ swzc)) = p1;
            *reinterpret_cast<u32x2*>(basew + ((qo + 16) ^ swzc)) = p2;
            *reinterpret_cast<u32x2*>(basew + ((qo + 24) ^ swzc)) = p3;
            __syncthreads();
        }
    }

    // ---- epilogue: C row = co (verified layout), col = pos -> coalesced ----
    int wcol = pos0 + l31;
    float aw = alds[wcol];                // faithful broadcast: alpha[WIDTH]
#pragma unroll
    for (int reg = 0; reg < 16; ++reg) {
        int rr = (reg & 3) + 8 * (reg >> 2) + 4 * hi;
        int coa = co0 + rr;
        int cob = co0 + 32 + rr;
        out[((size_t)(n * COUT + coa) * HH + h) * WW + wcol] = (float)acc0[reg] * aw;
        out[((size_t)(n * COUT + cob) * HH + h) * WW + wcol] = (float)acc1[reg] * aw;
    }
}

extern "C" void kernel_launch(void* const* d_in, const int* in_sizes, int n_in,
                              void* d_out, int out_size, void* d_ws, size_t ws_size,
                              hipStream_t stream) {
    const float* x  = (const float*)d_in[0];
    const float* wt = (const float*)d_in[1];
    float* out = (float*)d_out;

    char* ws = (char*)d_ws;
    const size_t PX_BYTES = (size_t)NIMG * HH * WW * 4 * sizeof(u64);  // 8 MiB
    const size_t WB_BYTES = (size_t)COUT * 2304;                       // 288 KiB
    const size_t AL_BYTES = 512;
    if (ws_size < PX_BYTES + WB_BYTES + AL_BYTES) return;
    u64*   px    = (u64*)ws;
    i8*    wbuf  = (i8*)(ws + PX_BYTES);
    float* alpha = (float*)(ws + PX_BYTES + WB_BYTES);

    pack_x_kernel<<<NIMG * HH * WW / 256, 256, 0, stream>>>(x, px);
    pack_w_kernel<<<COUT, 256, 0, stream>>>(wt, wbuf, alpha);
    conv_kernel<<<NIMG * HH, 512, 0, stream>>>(px, wbuf, alpha, out);
}

// Round 14
// 168.664 us; speedup vs baseline: 1.6139x; 1.1453x over previous
//
#include <hip/hip_runtime.h>
#include <stdint.h>

#define CIN   256
#define COUT  128
#define HH    128
#define WW    128
#define NIMG  16

typedef unsigned long long u64;
typedef unsigned int u32;
typedef unsigned short u16;
typedef u32 u32x2 __attribute__((ext_vector_type(2)));
typedef u32 u32x4 __attribute__((ext_vector_type(4)));
typedef int i32x4 __attribute__((ext_vector_type(4)));
typedef int i32x16 __attribute__((ext_vector_type(16)));
typedef signed char i8;

// ---------------------------------------------------------------------------
// Pack sign bits of x: px[(n*HH+h)*WW + w][word 0..3]; bit (c&63) of word
// (c>>6) = (x[n][c][h][w] > 0). 32 B per position.
// ---------------------------------------------------------------------------
__global__ __launch_bounds__(256) void pack_x_kernel(const float* __restrict__ x,
                                                     u64* __restrict__ px) {
    int t = blockIdx.x * 256 + threadIdx.x;
    int w = t & (WW - 1);
    int h = (t >> 7) & (HH - 1);
    int n = t >> 14;
    const float* xp = x + (size_t)n * CIN * HH * WW + (size_t)h * WW + w;
    u64 words[4];
#pragma unroll
    for (int wd = 0; wd < 4; ++wd) {
        u64 acc = 0;
#pragma unroll 16
        for (int cc = 0; cc < 64; ++cc) {
            float v = xp[(size_t)(wd * 64 + cc) * (HH * WW)];
            acc |= (u64)(v > 0.0f) << cc;
        }
        words[wd] = acc;
    }
    ulonglong2* o = reinterpret_cast<ulonglong2*>(px + (size_t)t * 4);
    o[0] = make_ulonglong2(words[0], words[1]);
    o[1] = make_ulonglong2(words[2], words[3]);
}

// ---------------------------------------------------------------------------
// Weights to i8 +-1, K-major per co: wb[co*2304 + tap*256 + c]; alpha[co].
// ---------------------------------------------------------------------------
__global__ __launch_bounds__(256) void pack_w_kernel(const float* __restrict__ wt,
                                                     i8* __restrict__ wb,
                                                     float* __restrict__ alpha) {
    int co = blockIdx.x;
    int c  = threadIdx.x;
    int lane = c & 63;
    int word = c >> 6;
    const float* wp = wt + ((size_t)co * CIN + c) * 9;
    float asum = 0.0f;
#pragma unroll
    for (int k = 0; k < 9; ++k) {
        float v = wp[k];
        asum += fabsf(v);
        wb[(size_t)co * 2304 + k * 256 + c] = (v > 0.0f) ? (i8)1 : (i8)-1;
    }
    __shared__ float red[4];
    for (int off = 32; off > 0; off >>= 1) asum += __shfl_down(asum, off);
    if (lane == 0) red[word] = asum;
    __syncthreads();
    if (c == 0) alpha[co] = (red[0] + red[1] + red[2] + red[3]) * (1.0f / 2304.0f);
}

// 16 k-bits -> 16 i8 bytes of +-1 (v9-proven nibble spread + perm).
__device__ __forceinline__ i32x4 expand16(u32 v) {
    u32 o0 = __builtin_amdgcn_perm(0x01010101u, 0xFFFFFFFFu,
              ((((v      ) & 15u) * 0x00204081u) & 0x01010101u) << 2);
    u32 o1 = __builtin_amdgcn_perm(0x01010101u, 0xFFFFFFFFu,
              ((((v >>  4) & 15u) * 0x00204081u) & 0x01010101u) << 2);
    u32 o2 = __builtin_amdgcn_perm(0x01010101u, 0xFFFFFFFFu,
              ((((v >>  8) & 15u) * 0x00204081u) & 0x01010101u) << 2);
    u32 o3 = __builtin_amdgcn_perm(0x01010101u, 0xFFFFFFFFu,
              ((((v >> 12) & 15u) * 0x00204081u) & 0x01010101u) << 2);
    i32x4 r = {(int)o0, (int)o1, (int)o2, (int)o3};
    return r;
}

// ---------------------------------------------------------------------------
// XNOR conv v11 -- v10 + halo fix (3rd resubmit; R11-R13 container drops).
// v10 BUG: halo stored as zero BITS in packed xlt; expand16(0) = 16 bytes
// of -1 (0xFF), not 0 -> border taps contributed -sum(w) instead of 0
// (absmax 84, border-only). Packed bits cannot represent "pad=0"; zero the
// EXPANDED fragment in registers instead: AND-mask with validity
// (col in [1,128] && row in-bounds). Row validity is wave-uniform (scalar
// branch); col validity = 4 v_and per fragment on the idle VALU pipe.
// Rest identical to v10: X bit-packed in LDS (12.5KB, transposed u16
// planes xlt[row][k16][col], conflict-free 2B reads), expand-in-regs,
// W 2x16KB dbuf swizzled LDS (v9-proven), wave tile 64co x 64pos, 4 waves.
// out[n][co][h][w] = (float)acc * alpha[w]   (alpha by WIDTH!)
// ---------------------------------------------------------------------------
__global__ __launch_bounds__(256, 3) void conv_kernel(const u64* __restrict__ px,
                                                      const i8* __restrict__ wb,
                                                      const float* __restrict__ alpha,
                                                      float* __restrict__ out) {
    __shared__ u16 xlt[3][16][130];                  // 12480 B, packed bits
    __shared__ __align__(16) i8 wl[2][128 * 128];    // 32768 B, swizzled
    __shared__ float alds[WW];                       // 512 B

    int tid = threadIdx.x;
    int bid = blockIdx.x;                 // n*128 + h
    int h = bid & (HH - 1);
    int n = bid >> 7;

    if (tid < WW) alds[tid] = alpha[tid];

    // ---- W chunk 0: issue global loads early (64 B/thread) ----
    int sco = tid >> 1, sq = tid & 1;     // 128 co x 2 halves of 128k-chunk
    u32x4 g0, g1, g2, g3;
    {
        const u32x4* s = reinterpret_cast<const u32x4*>(
            wb + (size_t)sco * 2304 + sq * 64);
        g0 = s[0]; g1 = s[1]; g2 = s[2]; g3 = s[3];
    }

    // ---- X stage: packed bits -> transposed u16 planes (halo = 0 bits;
    //      decoded halo is masked in-register in the main loop) ----
    for (int t = tid; t < 390; t += 256) {
        int r = (t >= 260) ? 2 : ((t >= 130) ? 1 : 0);
        int p = t - r * 130;              // col 0..129; position w = p-1
        int gh = h - 1 + r;
        u32 bw[8] = {0, 0, 0, 0, 0, 0, 0, 0};
        if ((p >= 1) && (p <= 128) && (gh >= 0) && (gh < HH)) {
            const u32x4* s = reinterpret_cast<const u32x4*>(
                px + (size_t)((n * HH + gh) * WW + (p - 1)) * 4);
            u32x4 a = s[0], b = s[1];
            bw[0] = a.x; bw[1] = a.y; bw[2] = a.z; bw[3] = a.w;
            bw[4] = b.x; bw[5] = b.y; bw[6] = b.z; bw[7] = b.w;
        }
#pragma unroll
        for (int k16 = 0; k16 < 16; ++k16)
            xlt[r][k16][p] = (u16)(bw[k16 >> 1] >> ((k16 & 1) * 16));
    }

    // ---- write W chunk 0 (swizzled 8B granule, v9-identical) ----
    {
        i8* basew = wl[0] + (sco << 7);
        int swzc = (sco & 15) << 3;
        int qo = sq * 64;
        u32x2 p0 = {g0.x, g0.y}, p1 = {g0.z, g0.w};
        u32x2 p2 = {g1.x, g1.y}, p3 = {g1.z, g1.w};
        u32x2 p4 = {g2.x, g2.y}, p5 = {g2.z, g2.w};
        u32x2 p6 = {g3.x, g3.y}, p7 = {g3.z, g3.w};
        *reinterpret_cast<u32x2*>(basew + ((qo + 0)  ^ swzc)) = p0;
        *reinterpret_cast<u32x2*>(basew + ((qo + 8)  ^ swzc)) = p1;
        *reinterpret_cast<u32x2*>(basew + ((qo + 16) ^ swzc)) = p2;
        *reinterpret_cast<u32x2*>(basew + ((qo + 24) ^ swzc)) = p3;
        *reinterpret_cast<u32x2*>(basew + ((qo + 32) ^ swzc)) = p4;
        *reinterpret_cast<u32x2*>(basew + ((qo + 40) ^ swzc)) = p5;
        *reinterpret_cast<u32x2*>(basew + ((qo + 48) ^ swzc)) = p6;
        *reinterpret_cast<u32x2*>(basew + ((qo + 56) ^ swzc)) = p7;
    }
    __syncthreads();

    // ---- main K loop: 18 chunks (half-tap = 128 k), 4 k-steps each ----
    int lane = tid & 63;
    int wave = tid >> 6;                  // 0..3
    int l31 = lane & 31;
    int hi  = lane >> 5;
    int co0  = (wave & 1) * 64;           // co groups: co0, co0+32
    int pos0 = (wave >> 1) * 64;          // pos groups: pos0, pos0+32

    i32x16 accA0 = {}, accA1 = {}, accB0 = {}, accB1 = {};  // [pos][co]

    int swzw = (l31 & 15) << 3;

#pragma unroll 1
    for (int ch = 0; ch < 18; ++ch) {
        int nxt = ch + 1;
        if (nxt < 18) {                   // prefetch next W chunk to regs
            const u32x4* s = reinterpret_cast<const u32x4*>(
                wb + (size_t)sco * 2304 + nxt * 128 + sq * 64);
            g0 = s[0]; g1 = s[1]; g2 = s[2]; g3 = s[3];
        }
        int tap = ch >> 1;
        int k16b = (ch & 1) * 8;          // u16-plane base within tap
        int r   = tap / 3;
        int dwi = tap - r * 3;            // col = pos + dwi (halo absorbs -1)
        int colA = pos0 + l31 + dwi;
        int colB = colA + 32;
        // Halo validity: row (wave-uniform) x col (per-lane).
        bool rowOK = (r == 1) || (r == 0 ? (h > 0) : (h < HH - 1));
        int mA = (rowOK && colA >= 1 && colA <= 128) ? -1 : 0;
        int mB = (rowOK && colB >= 1 && colB <= 128) ? -1 : 0;
        i32x4 mvA = {mA, mA, mA, mA};
        i32x4 mvB = {mB, mB, mB, mB};
        const i8* wbuf = wl[ch & 1];
        const i8* wr0 = wbuf + ((co0 + l31) << 7);
        const i8* wr1 = wbuf + ((co0 + 32 + l31) << 7);
#pragma unroll
        for (int ks = 0; ks < 4; ++ks) {
            int k16 = k16b + ks * 2 + hi;
            i32x4 xfA = expand16((u32)xlt[r][k16][colA]) & mvA;  // halo -> 0
            i32x4 xfB = expand16((u32)xlt[r][k16][colB]) & mvB;
            int kk = ks * 32 + hi * 16;
            u32x2 wa0 = *reinterpret_cast<const u32x2*>(wr0 + (kk ^ swzw));
            u32x2 wa1 = *reinterpret_cast<const u32x2*>(wr0 + ((kk + 8) ^ swzw));
            u32x2 wc0 = *reinterpret_cast<const u32x2*>(wr1 + (kk ^ swzw));
            u32x2 wc1 = *reinterpret_cast<const u32x2*>(wr1 + ((kk + 8) ^ swzw));
            i32x4 wf0 = {(int)wa0.x, (int)wa0.y, (int)wa1.x, (int)wa1.y};
            i32x4 wf1 = {(int)wc0.x, (int)wc0.y, (int)wc1.x, (int)wc1.y};
            accA0 = __builtin_amdgcn_mfma_i32_32x32x32_i8(wf0, xfA, accA0, 0, 0, 0);
            accA1 = __builtin_amdgcn_mfma_i32_32x32x32_i8(wf1, xfA, accA1, 0, 0, 0);
            accB0 = __builtin_amdgcn_mfma_i32_32x32x32_i8(wf0, xfB, accB0, 0, 0, 0);
            accB1 = __builtin_amdgcn_mfma_i32_32x32x32_i8(wf1, xfB, accB1, 0, 0, 0);
        }
        __syncthreads();                  // reads of wl[ch&1] complete
        if (nxt < 18) {
            i8* basew = wl[nxt & 1] + (sco << 7);
            int swzc = (sco & 15) << 3;
            int qo = sq * 64;
            u32x2 p0 = {g0.x, g0.y}, p1 = {g0.z, g0.w};
            u32x2 p2 = {g1.x, g1.y}, p3 = {g1.z, g1.w};
            u32x2 p4 = {g2.x, g2.y}, p5 = {g2.z, g2.w};
            u32x2 p6 = {g3.x, g3.y}, p7 = {g3.z, g3.w};
            *reinterpret_cast<u32x2*>(basew + ((qo + 0)  ^ swzc)) = p0;
            *reinterpret_cast<u32x2*>(basew + ((qo + 8)  ^ swzc)) = p1;
            *reinterpret_cast<u32x2*>(basew + ((qo + 16) ^ swzc)) = p2;
            *reinterpret_cast<u32x2*>(basew + ((qo + 24) ^ swzc)) = p3;
            *reinterpret_cast<u32x2*>(basew + ((qo + 32) ^ swzc)) = p4;
            *reinterpret_cast<u32x2*>(basew + ((qo + 40) ^ swzc)) = p5;
            *reinterpret_cast<u32x2*>(basew + ((qo + 48) ^ swzc)) = p6;
            *reinterpret_cast<u32x2*>(basew + ((qo + 56) ^ swzc)) = p7;
            __syncthreads();
        }
    }

    // ---- epilogue: C col = lane&31 = pos (verified layout) ----
#pragma unroll
    for (int half = 0; half < 2; ++half) {
        int wcol = pos0 + half * 32 + l31;
        float aw = alds[wcol];            // faithful broadcast: alpha[WIDTH]
        i32x16 a0 = half ? accB0 : accA0;
        i32x16 a1 = half ? accB1 : accA1;
#pragma unroll
        for (int reg = 0; reg < 16; ++reg) {
            int rr = (reg & 3) + 8 * (reg >> 2) + 4 * hi;
            out[((size_t)(n * COUT + co0 + rr) * HH + h) * WW + wcol] =
                (float)a0[reg] * aw;
            out[((size_t)(n * COUT + co0 + 32 + rr) * HH + h) * WW + wcol] =
                (float)a1[reg] * aw;
        }
    }
}

extern "C" void kernel_launch(void* const* d_in, const int* in_sizes, int n_in,
                              void* d_out, int out_size, void* d_ws, size_t ws_size,
                              hipStream_t stream) {
    const float* x  = (const float*)d_in[0];
    const float* wt = (const float*)d_in[1];
    float* out = (float*)d_out;

    char* ws = (char*)d_ws;
    const size_t PX_BYTES = (size_t)NIMG * HH * WW * 4 * sizeof(u64);  // 8 MiB
    const size_t WB_BYTES = (size_t)COUT * 2304;                       // 288 KiB
    const size_t AL_BYTES = 512;
    if (ws_size < PX_BYTES + WB_BYTES + AL_BYTES) return;
    u64*   px    = (u64*)ws;
    i8*    wbuf  = (i8*)(ws + PX_BYTES);
    float* alpha = (float*)(ws + PX_BYTES + WB_BYTES);

    pack_x_kernel<<<NIMG * HH * WW / 256, 256, 0, stream>>>(x, px);
    pack_w_kernel<<<COUT, 256, 0, stream>>>(wt, wbuf, alpha);
    conv_kernel<<<NIMG * HH, 256, 0, stream>>>(px, wbuf, alpha, out);
}

// Round 15
// 167.113 us; speedup vs baseline: 1.6289x; 1.0093x over previous
//
#include <hip/hip_runtime.h>
#include <stdint.h>

#define CIN   256
#define COUT  128
#define HH    128
#define WW    128
#define NIMG  16

typedef unsigned long long u64;
typedef unsigned int u32;
typedef unsigned short u16;
typedef u32 u32x2 __attribute__((ext_vector_type(2)));
typedef u32 u32x4 __attribute__((ext_vector_type(4)));
typedef int i32x4 __attribute__((ext_vector_type(4)));
typedef int i32x16 __attribute__((ext_vector_type(16)));
typedef signed char i8;

// ---------------------------------------------------------------------------
// Pack sign bits of x: px[(n*HH+h)*WW + w][word 0..3]; bit (c&63) of word
// (c>>6) = (x[n][c][h][w] > 0). 32 B per position. ~43 us (HBM roofline).
// ---------------------------------------------------------------------------
__global__ __launch_bounds__(256) void pack_x_kernel(const float* __restrict__ x,
                                                     u64* __restrict__ px) {
    int t = blockIdx.x * 256 + threadIdx.x;
    int w = t & (WW - 1);
    int h = (t >> 7) & (HH - 1);
    int n = t >> 14;
    const float* xp = x + (size_t)n * CIN * HH * WW + (size_t)h * WW + w;
    u64 words[4];
#pragma unroll
    for (int wd = 0; wd < 4; ++wd) {
        u64 acc = 0;
#pragma unroll 16
        for (int cc = 0; cc < 64; ++cc) {
            float v = xp[(size_t)(wd * 64 + cc) * (HH * WW)];
            acc |= (u64)(v > 0.0f) << cc;
        }
        words[wd] = acc;
    }
    ulonglong2* o = reinterpret_cast<ulonglong2*>(px + (size_t)t * 4);
    o[0] = make_ulonglong2(words[0], words[1]);
    o[1] = make_ulonglong2(words[2], words[3]);
}

// ---------------------------------------------------------------------------
// Weights to i8 +-1, K-major per co: wb[co*2304 + tap*256 + c]; alpha[co].
// ---------------------------------------------------------------------------
__global__ __launch_bounds__(256) void pack_w_kernel(const float* __restrict__ wt,
                                                     i8* __restrict__ wb,
                                                     float* __restrict__ alpha) {
    int co = blockIdx.x;
    int c  = threadIdx.x;
    int lane = c & 63;
    int word = c >> 6;
    const float* wp = wt + ((size_t)co * CIN + c) * 9;
    float asum = 0.0f;
#pragma unroll
    for (int k = 0; k < 9; ++k) {
        float v = wp[k];
        asum += fabsf(v);
        wb[(size_t)co * 2304 + k * 256 + c] = (v > 0.0f) ? (i8)1 : (i8)-1;
    }
    __shared__ float red[4];
    for (int off = 32; off > 0; off >>= 1) asum += __shfl_down(asum, off);
    if (lane == 0) red[word] = asum;
    __syncthreads();
    if (c == 0) alpha[co] = (red[0] + red[1] + red[2] + red[3]) * (1.0f / 2304.0f);
}

// 16 k-bits -> 16 i8 bytes of +-1 (v9-proven nibble spread + perm).
__device__ __forceinline__ i32x4 expand16(u32 v) {
    u32 o0 = __builtin_amdgcn_perm(0x01010101u, 0xFFFFFFFFu,
              ((((v      ) & 15u) * 0x00204081u) & 0x01010101u) << 2);
    u32 o1 = __builtin_amdgcn_perm(0x01010101u, 0xFFFFFFFFu,
              ((((v >>  4) & 15u) * 0x00204081u) & 0x01010101u) << 2);
    u32 o2 = __builtin_amdgcn_perm(0x01010101u, 0xFFFFFFFFu,
              ((((v >>  8) & 15u) * 0x00204081u) & 0x01010101u) << 2);
    u32 o3 = __builtin_amdgcn_perm(0x01010101u, 0xFFFFFFFFu,
              ((((v >> 12) & 15u) * 0x00204081u) & 0x01010101u) << 2);
    i32x4 r = {(int)o0, (int)o1, (int)o2, (int)o3};
    return r;
}

// ---------------------------------------------------------------------------
// XNOR conv v12 -- v11 (passed, absmax 0, conv ~120us) with single-barrier
// pipelined W staging. v11 spent 2 barriers per chunk (35 total): compute ->
// bar -> vmcnt+ds_write -> bar. Dbuf insight: writes to wl[nxt] overlap
// reads of wl[cur] (different buffers); the overwrite hazard on wl[nxt]
// (read 2 chunks ago) is covered by the intervening barrier. New loop:
// { compute(cur); ds_write(nxt)<-g; g=load(nxt+1); barrier } = 17 barriers,
// prefetch-to-use distance = one full compute section (~700cyc, vmcnt
// hidden). Compute/layouts/masks byte-identical to v11.
// Pipe model: MFMA 35us + LDS ~40us + VALU ~25us overlapped at 12 waves/CU.
// out[n][co][h][w] = (float)acc * alpha[w]   (alpha by WIDTH!)
// ---------------------------------------------------------------------------
__global__ __launch_bounds__(256, 3) void conv_kernel(const u64* __restrict__ px,
                                                      const i8* __restrict__ wb,
                                                      const float* __restrict__ alpha,
                                                      float* __restrict__ out) {
    __shared__ u16 xlt[3][16][130];                  // 12480 B, packed bits
    __shared__ __align__(16) i8 wl[2][128 * 128];    // 32768 B, swizzled
    __shared__ float alds[WW];                       // 512 B

    int tid = threadIdx.x;
    int bid = blockIdx.x;                 // n*128 + h
    int h = bid & (HH - 1);
    int n = bid >> 7;

    if (tid < WW) alds[tid] = alpha[tid];

    int sco = tid >> 1, sq = tid & 1;     // 128 co x 2 halves of 128k-chunk
    int swzc = (sco & 15) << 3;
    i8* wbase0 = wl[0] + (sco << 7);
    i8* wbase1 = wl[1] + (sco << 7);
    int qo = sq * 64;

    // ---- load W chunk 0 ----
    u32x4 g0, g1, g2, g3;
    {
        const u32x4* s = reinterpret_cast<const u32x4*>(
            wb + (size_t)sco * 2304 + sq * 64);
        g0 = s[0]; g1 = s[1]; g2 = s[2]; g3 = s[3];
    }

    // ---- X stage: packed bits -> transposed u16 planes (halo = 0 bits;
    //      decoded halo is masked in-register in the main loop) ----
    for (int t = tid; t < 390; t += 256) {
        int r = (t >= 260) ? 2 : ((t >= 130) ? 1 : 0);
        int p = t - r * 130;              // col 0..129; position w = p-1
        int gh = h - 1 + r;
        u32 bw[8] = {0, 0, 0, 0, 0, 0, 0, 0};
        if ((p >= 1) && (p <= 128) && (gh >= 0) && (gh < HH)) {
            const u32x4* s = reinterpret_cast<const u32x4*>(
                px + (size_t)((n * HH + gh) * WW + (p - 1)) * 4);
            u32x4 a = s[0], b = s[1];
            bw[0] = a.x; bw[1] = a.y; bw[2] = a.z; bw[3] = a.w;
            bw[4] = b.x; bw[5] = b.y; bw[6] = b.z; bw[7] = b.w;
        }
#pragma unroll
        for (int k16 = 0; k16 < 16; ++k16)
            xlt[r][k16][p] = (u16)(bw[k16 >> 1] >> ((k16 & 1) * 16));
    }

    // ---- write W chunk 0, prefetch chunk 1, one barrier ----
    {
        u32x2 p0 = {g0.x, g0.y}, p1 = {g0.z, g0.w};
        u32x2 p2 = {g1.x, g1.y}, p3 = {g1.z, g1.w};
        u32x2 p4 = {g2.x, g2.y}, p5 = {g2.z, g2.w};
        u32x2 p6 = {g3.x, g3.y}, p7 = {g3.z, g3.w};
        *reinterpret_cast<u32x2*>(wbase0 + ((qo + 0)  ^ swzc)) = p0;
        *reinterpret_cast<u32x2*>(wbase0 + ((qo + 8)  ^ swzc)) = p1;
        *reinterpret_cast<u32x2*>(wbase0 + ((qo + 16) ^ swzc)) = p2;
        *reinterpret_cast<u32x2*>(wbase0 + ((qo + 24) ^ swzc)) = p3;
        *reinterpret_cast<u32x2*>(wbase0 + ((qo + 32) ^ swzc)) = p4;
        *reinterpret_cast<u32x2*>(wbase0 + ((qo + 40) ^ swzc)) = p5;
        *reinterpret_cast<u32x2*>(wbase0 + ((qo + 48) ^ swzc)) = p6;
        *reinterpret_cast<u32x2*>(wbase0 + ((qo + 56) ^ swzc)) = p7;
    }
    {
        const u32x4* s = reinterpret_cast<const u32x4*>(
            wb + (size_t)sco * 2304 + 128 + sq * 64);
        g0 = s[0]; g1 = s[1]; g2 = s[2]; g3 = s[3];
    }
    __syncthreads();

    // ---- main K loop: 18 chunks, ONE barrier per chunk ----
    int lane = tid & 63;
    int wave = tid >> 6;                  // 0..3
    int l31 = lane & 31;
    int hi  = lane >> 5;
    int co0  = (wave & 1) * 64;           // co groups: co0, co0+32
    int pos0 = (wave >> 1) * 64;          // pos groups: pos0, pos0+32

    i32x16 accA0 = {}, accA1 = {}, accB0 = {}, accB1 = {};  // [pos][co]

    int swzw = (l31 & 15) << 3;

#pragma unroll 1
    for (int ch = 0; ch < 18; ++ch) {
        // ---- compute on wl[ch&1] (v11-identical) ----
        int tap = ch >> 1;
        int k16b = (ch & 1) * 8;          // u16-plane base within tap
        int r   = tap / 3;
        int dwi = tap - r * 3;            // col = pos + dwi (halo absorbs -1)
        int colA = pos0 + l31 + dwi;
        int colB = colA + 32;
        bool rowOK = (r == 1) || (r == 0 ? (h > 0) : (h < HH - 1));
        int mA = (rowOK && colA >= 1 && colA <= 128) ? -1 : 0;
        int mB = (rowOK && colB >= 1 && colB <= 128) ? -1 : 0;
        i32x4 mvA = {mA, mA, mA, mA};
        i32x4 mvB = {mB, mB, mB, mB};
        const i8* wbuf = wl[ch & 1];
        const i8* wr0 = wbuf + ((co0 + l31) << 7);
        const i8* wr1 = wbuf + ((co0 + 32 + l31) << 7);
#pragma unroll
        for (int ks = 0; ks < 4; ++ks) {
            int k16 = k16b + ks * 2 + hi;
            i32x4 xfA = expand16((u32)xlt[r][k16][colA]) & mvA;  // halo -> 0
            i32x4 xfB = expand16((u32)xlt[r][k16][colB]) & mvB;
            int kk = ks * 32 + hi * 16;
            u32x2 wa0 = *reinterpret_cast<const u32x2*>(wr0 + (kk ^ swzw));
            u32x2 wa1 = *reinterpret_cast<const u32x2*>(wr0 + ((kk + 8) ^ swzw));
            u32x2 wc0 = *reinterpret_cast<const u32x2*>(wr1 + (kk ^ swzw));
            u32x2 wc1 = *reinterpret_cast<const u32x2*>(wr1 + ((kk + 8) ^ swzw));
            i32x4 wf0 = {(int)wa0.x, (int)wa0.y, (int)wa1.x, (int)wa1.y};
            i32x4 wf1 = {(int)wc0.x, (int)wc0.y, (int)wc1.x, (int)wc1.y};
            accA0 = __builtin_amdgcn_mfma_i32_32x32x32_i8(wf0, xfA, accA0, 0, 0, 0);
            accA1 = __builtin_amdgcn_mfma_i32_32x32x32_i8(wf1, xfA, accA1, 0, 0, 0);
            accB0 = __builtin_amdgcn_mfma_i32_32x32x32_i8(wf0, xfB, accB0, 0, 0, 0);
            accB1 = __builtin_amdgcn_mfma_i32_32x32x32_i8(wf1, xfB, accB1, 0, 0, 0);
        }
        // ---- stage chunk ch+1 into the OTHER buffer (no barrier needed
        //      before: its readers finished at the ch-1 barrier), then
        //      prefetch chunk ch+2, then ONE barrier ----
        if (ch < 17) {
            i8* basew = (ch & 1) ? wbase0 : wbase1;   // wl[(ch+1)&1]
            u32x2 p0 = {g0.x, g0.y}, p1 = {g0.z, g0.w};
            u32x2 p2 = {g1.x, g1.y}, p3 = {g1.z, g1.w};
            u32x2 p4 = {g2.x, g2.y}, p5 = {g2.z, g2.w};
            u32x2 p6 = {g3.x, g3.y}, p7 = {g3.z, g3.w};
            *reinterpret_cast<u32x2*>(basew + ((qo + 0)  ^ swzc)) = p0;
            *reinterpret_cast<u32x2*>(basew + ((qo + 8)  ^ swzc)) = p1;
            *reinterpret_cast<u32x2*>(basew + ((qo + 16) ^ swzc)) = p2;
            *reinterpret_cast<u32x2*>(basew + ((qo + 24) ^ swzc)) = p3;
            *reinterpret_cast<u32x2*>(basew + ((qo + 32) ^ swzc)) = p4;
            *reinterpret_cast<u32x2*>(basew + ((qo + 40) ^ swzc)) = p5;
            *reinterpret_cast<u32x2*>(basew + ((qo + 48) ^ swzc)) = p6;
            *reinterpret_cast<u32x2*>(basew + ((qo + 56) ^ swzc)) = p7;
            if (ch < 16) {
                const u32x4* s = reinterpret_cast<const u32x4*>(
                    wb + (size_t)sco * 2304 + (ch + 2) * 128 + sq * 64);
                g0 = s[0]; g1 = s[1]; g2 = s[2]; g3 = s[3];
            }
            __syncthreads();
        }
    }

    // ---- epilogue: C col = lane&31 = pos (verified layout) ----
#pragma unroll
    for (int half = 0; half < 2; ++half) {
        int wcol = pos0 + half * 32 + l31;
        float aw = alds[wcol];            // faithful broadcast: alpha[WIDTH]
        i32x16 a0 = half ? accB0 : accA0;
        i32x16 a1 = half ? accB1 : accA1;
#pragma unroll
        for (int reg = 0; reg < 16; ++reg) {
            int rr = (reg & 3) + 8 * (reg >> 2) + 4 * hi;
            out[((size_t)(n * COUT + co0 + rr) * HH + h) * WW + wcol] =
                (float)a0[reg] * aw;
            out[((size_t)(n * COUT + co0 + 32 + rr) * HH + h) * WW + wcol] =
                (float)a1[reg] * aw;
        }
    }
}

extern "C" void kernel_launch(void* const* d_in, const int* in_sizes, int n_in,
                              void* d_out, int out_size, void* d_ws, size_t ws_size,
                              hipStream_t stream) {
    const float* x  = (const float*)d_in[0];
    const float* wt = (const float*)d_in[1];
    float* out = (float*)d_out;

    char* ws = (char*)d_ws;
    const size_t PX_BYTES = (size_t)NIMG * HH * WW * 4 * sizeof(u64);  // 8 MiB
    const size_t WB_BYTES = (size_t)COUT * 2304;                       // 288 KiB
    const size_t AL_BYTES = 512;
    if (ws_size < PX_BYTES + WB_BYTES + AL_BYTES) return;
    u64*   px    = (u64*)ws;
    i8*    wbuf  = (i8*)(ws + PX_BYTES);
    float* alpha = (float*)(ws + PX_BYTES + WB_BYTES);

    pack_x_kernel<<<NIMG * HH * WW / 256, 256, 0, stream>>>(x, px);
    pack_w_kernel<<<COUT, 256, 0, stream>>>(wt, wbuf, alpha);
    conv_kernel<<<NIMG * HH, 256, 0, stream>>>(px, wbuf, alpha, out);
}

// Round 16
// 150.190 us; speedup vs baseline: 1.8124x; 1.1127x over previous
//
#include <hip/hip_runtime.h>
#include <stdint.h>

#define CIN   256
#define COUT  128
#define HH    128
#define WW    128
#define NIMG  16

typedef unsigned long long u64;
typedef unsigned int u32;
typedef unsigned short u16;
typedef u32 u32x4 __attribute__((ext_vector_type(4)));
typedef int i32x4 __attribute__((ext_vector_type(4)));
typedef int i32x16 __attribute__((ext_vector_type(16)));
typedef signed char i8;

// ---------------------------------------------------------------------------
// Pack sign bits of x: px[(n*HH+h)*WW + w][word 0..3]; bit (c&63) of word
// (c>>6) = (x[n][c][h][w] > 0). 32 B per position. ~45 us (HBM roofline:
// reads 268 MB fp32).
// ---------------------------------------------------------------------------
__global__ __launch_bounds__(256) void pack_x_kernel(const float* __restrict__ x,
                                                     u64* __restrict__ px) {
    int t = blockIdx.x * 256 + threadIdx.x;
    int w = t & (WW - 1);
    int h = (t >> 7) & (HH - 1);
    int n = t >> 14;
    const float* xp = x + (size_t)n * CIN * HH * WW + (size_t)h * WW + w;
    u64 words[4];
#pragma unroll
    for (int wd = 0; wd < 4; ++wd) {
        u64 acc = 0;
#pragma unroll 16
        for (int cc = 0; cc < 64; ++cc) {
            float v = xp[(size_t)(wd * 64 + cc) * (HH * WW)];
            acc |= (u64)(v > 0.0f) << cc;
        }
        words[wd] = acc;
    }
    ulonglong2* o = reinterpret_cast<ulonglong2*>(px + (size_t)t * 4);
    o[0] = make_ulonglong2(words[0], words[1]);
    o[1] = make_ulonglong2(words[2], words[3]);
}

// ---------------------------------------------------------------------------
// W -> k16-group-major i8 table wg[k16][co][16] (k16 = tap*16 + c/16, byte =
// c%16): a wave's MFMA A-fragment (16 k-bytes of one co) is 16 contiguous
// bytes, and 32 lanes' co are contiguous -> fully coalesced dwordx4 loads.
// Also: wsum[pat][co] (i16) = sum over taps VALID in border pattern pat of
// (2*popc(wbits[tap]) - 256) = sum_valid w; alpha[co] = mean|W|.
// ---------------------------------------------------------------------------
__global__ __launch_bounds__(256) void pack_w_kernel(const float* __restrict__ wt,
                                                     i8* __restrict__ wg,
                                                     short* __restrict__ wsum,
                                                     float* __restrict__ alpha) {
    int co = blockIdx.x;
    int c  = threadIdx.x;            // input channel
    int lane = c & 63;
    int word = c >> 6;
    __shared__ u64 wsh[9][4];
    __shared__ int pct[9];
    __shared__ float red[4];
    const float* wp = wt + ((size_t)co * CIN + c) * 9;
    float asum = 0.0f;
#pragma unroll
    for (int k = 0; k < 9; ++k) {
        float v = wp[k];
        asum += fabsf(v);
        u64 m = __ballot(v > 0.0f);
        if (lane == 0) wsh[k][word] = m;
        int k16g = k * 16 + (c >> 4);
        wg[((size_t)k16g * COUT + co) * 16 + (c & 15)] = (v > 0.0f) ? (i8)1 : (i8)-1;
    }
    for (int off = 32; off > 0; off >>= 1) asum += __shfl_down(asum, off);
    if (lane == 0) red[word] = asum;
    __syncthreads();
    if (c < 9)
        pct[c] = __popcll(wsh[c][0]) + __popcll(wsh[c][1]) +
                 __popcll(wsh[c][2]) + __popcll(wsh[c][3]);
    if (c == 0) alpha[co] = (red[0] + red[1] + red[2] + red[3]) * (1.0f / 2304.0f);
    __syncthreads();
    if (c < 9) {
        int pat = c, ht = pat / 3, wtp = pat % 3;
        int s = 0;
#pragma unroll
        for (int k = 0; k < 9; ++k) {
            int dh = k / 3 - 1, dw = k % 3 - 1;
            bool inv = (dh == -1 && ht == 0) || (dh == 1 && ht == 2) ||
                       (dw == -1 && wtp == 0) || (dw == 1 && wtp == 2);
            if (!inv) s += 2 * pct[k] - 256;   // sum of +-1 weights, valid taps
        }
        wsum[pat * COUT + co] = (short)s;
    }
}

// 16 k-bits -> 16 i8 bytes of {0,1} (spread only -- no select, no perm).
__device__ __forceinline__ i32x4 spread16(u32 v) {
    u32 o0 = (((v      ) & 15u) * 0x00204081u) & 0x01010101u;
    u32 o1 = (((v >>  4) & 15u) * 0x00204081u) & 0x01010101u;
    u32 o2 = (((v >>  8) & 15u) * 0x00204081u) & 0x01010101u;
    u32 o3 = (((v >> 12) & 15u) * 0x00204081u) & 0x01010101u;
    i32x4 r = {(int)o0, (int)o1, (int)o2, (int)o3};
    return r;
}

// ---------------------------------------------------------------------------
// XNOR conv v13 -- {0,1}-X algebra + W direct from L2. R15 forensics:
// conv ~113us == SERIAL SUM of pipes (MFMA 35 + VALU 26 + LDS 23 + stores)
// at 3 waves/SIMD -> no overlap; barriers weren't the cost (v12 neutral).
// Cuts: (1) X expands to {0,1} bytes (spread-only, no +-1 select, no border
// masks -- halo 0-bits ARE correct zero padding). True out = 2*S - Wsum
// where S = mfma(w, xb), Wsum = per-(pattern,co) sum of valid-tap weights
// (R7-proven table machinery). (2) W read directly from the 288-KB
// L2-resident wg[k16][co][16] table via coalesced dwordx4 -- no W LDS, no
// dbuf, ZERO main-loop barriers. LDS 46->15.5 KB -> 4 blocks/CU (16
// waves/CU). Per k-step: 2 ds_read_u16 + 2 spread + 2 global dwordx4 +
// 4 MFMA. Pipes: MFMA 35us (dominant), VALU ~18, LDS ~6, L2 ~17 shared.
// out[n][co][h][w] = (float)(2*S - wsum) * alpha[w]   (alpha by WIDTH!)
// ---------------------------------------------------------------------------
__global__ __launch_bounds__(256, 4) void conv_kernel(const u64* __restrict__ px,
                                                      const i8* __restrict__ wg,
                                                      const short* __restrict__ wsum,
                                                      const float* __restrict__ alpha,
                                                      float* __restrict__ out) {
    __shared__ u16 xlt[3][16][130];                  // 12480 B, packed bits
    __shared__ short wsl[9 * COUT];                  // 2304 B
    __shared__ float alds[WW];                       // 512 B

    int tid = threadIdx.x;
    int bid = blockIdx.x;                 // n*128 + h
    int h = bid & (HH - 1);
    int n = bid >> 7;

    if (tid < WW) alds[tid] = alpha[tid];
    {
        const u32* s = reinterpret_cast<const u32*>(wsum);
        u32* d = reinterpret_cast<u32*>(wsl);
        for (int i = tid; i < 9 * COUT / 2; i += 256) d[i] = s[i];
    }

    // ---- X stage: packed bits -> transposed u16 planes (halo = 0 bits ->
    //      decodes to xb=0 under spread16 == correct zero padding) ----
    for (int t = tid; t < 390; t += 256) {
        int r = (t >= 260) ? 2 : ((t >= 130) ? 1 : 0);
        int p = t - r * 130;              // col 0..129; position w = p-1
        int gh = h - 1 + r;
        u32 bw[8] = {0, 0, 0, 0, 0, 0, 0, 0};
        if ((p >= 1) && (p <= 128) && (gh >= 0) && (gh < HH)) {
            const u32x4* s = reinterpret_cast<const u32x4*>(
                px + (size_t)((n * HH + gh) * WW + (p - 1)) * 4);
            u32x4 a = s[0], b = s[1];
            bw[0] = a.x; bw[1] = a.y; bw[2] = a.z; bw[3] = a.w;
            bw[4] = b.x; bw[5] = b.y; bw[6] = b.z; bw[7] = b.w;
        }
#pragma unroll
        for (int k16 = 0; k16 < 16; ++k16)
            xlt[r][k16][p] = (u16)(bw[k16 >> 1] >> ((k16 & 1) * 16));
    }
    __syncthreads();                      // the ONLY barrier

    // ---- main K loop: 18 chunks x 4 k-steps, no barriers ----
    int lane = tid & 63;
    int wave = tid >> 6;                  // 0..3
    int l31 = lane & 31;
    int hi  = lane >> 5;
    int co0  = (wave & 1) * 64;           // co groups: co0, co0+32
    int pos0 = (wave >> 1) * 64;          // pos groups: pos0, pos0+32

    i32x16 accA0 = {}, accA1 = {}, accB0 = {}, accB1 = {};  // [pos][co]

#pragma unroll 1
    for (int ch = 0; ch < 18; ++ch) {
        int tap = ch >> 1;
        int k16b = (ch & 1) * 8;          // tap-local u16-plane base
        int r   = tap / 3;
        int dwi = tap - r * 3;            // col = pos + dwi (halo absorbs -1)
        int colA = pos0 + l31 + dwi;
        int colB = colA + 32;
        int k16gb = tap * 16 + k16b;      // global k16 for W table
#pragma unroll
        for (int ks = 0; ks < 4; ++ks) {
            int k16 = k16b + ks * 2 + hi;
            i32x4 xfA = spread16((u32)xlt[r][k16][colA]);   // {0,1} bytes
            i32x4 xfB = spread16((u32)xlt[r][k16][colB]);
            int k16g = k16gb + ks * 2 + hi;
            const i32x4* wp = reinterpret_cast<const i32x4*>(
                wg + ((size_t)k16g * COUT) * 16);
            i32x4 wf0 = wp[co0 + l31];         // coalesced 512B per 32 lanes
            i32x4 wf1 = wp[co0 + 32 + l31];
            accA0 = __builtin_amdgcn_mfma_i32_32x32x32_i8(wf0, xfA, accA0, 0, 0, 0);
            accA1 = __builtin_amdgcn_mfma_i32_32x32x32_i8(wf1, xfA, accA1, 0, 0, 0);
            accB0 = __builtin_amdgcn_mfma_i32_32x32x32_i8(wf0, xfB, accB0, 0, 0, 0);
            accB1 = __builtin_amdgcn_mfma_i32_32x32x32_i8(wf1, xfB, accB1, 0, 0, 0);
        }
    }

    // ---- epilogue: out = (2*S - wsum[pat][co]) * alpha[w] ----
    int hpat = (h == 0) ? 0 : ((h == HH - 1) ? 2 : 1);
#pragma unroll
    for (int half = 0; half < 2; ++half) {
        int wcol = pos0 + half * 32 + l31;
        float aw = alds[wcol];            // faithful broadcast: alpha[WIDTH]
        int wpat = (wcol == 0) ? 0 : ((wcol == WW - 1) ? 2 : 1);
        const short* wsp = &wsl[(hpat * 3 + wpat) * COUT];
        i32x16 a0 = half ? accB0 : accA0;
        i32x16 a1 = half ? accB1 : accA1;
#pragma unroll
        for (int reg = 0; reg < 16; ++reg) {
            int rr = (reg & 3) + 8 * (reg >> 2) + 4 * hi;
            int coa = co0 + rr;
            int cob = co0 + 32 + rr;
            out[((size_t)(n * COUT + coa) * HH + h) * WW + wcol] =
                (float)(2 * a0[reg] - (int)wsp[coa]) * aw;
            out[((size_t)(n * COUT + cob) * HH + h) * WW + wcol] =
                (float)(2 * a1[reg] - (int)wsp[cob]) * aw;
        }
    }
}

extern "C" void kernel_launch(void* const* d_in, const int* in_sizes, int n_in,
                              void* d_out, int out_size, void* d_ws, size_t ws_size,
                              hipStream_t stream) {
    const float* x  = (const float*)d_in[0];
    const float* wt = (const float*)d_in[1];
    float* out = (float*)d_out;

    char* ws = (char*)d_ws;
    const size_t PX_BYTES = (size_t)NIMG * HH * WW * 4 * sizeof(u64);  // 8 MiB
    const size_t WG_BYTES = (size_t)144 * COUT * 16;                   // 288 KiB
    const size_t WS_BYTES = (size_t)9 * COUT * sizeof(short);          // 2.25 KiB
    const size_t AL_BYTES = 512;
    if (ws_size < PX_BYTES + WG_BYTES + WS_BYTES + AL_BYTES) return;
    u64*   px    = (u64*)ws;
    i8*    wg    = (i8*)(ws + PX_BYTES);
    short* wsum  = (short*)(ws + PX_BYTES + WG_BYTES);
    float* alpha = (float*)(ws + PX_BYTES + WG_BYTES + WS_BYTES);

    pack_x_kernel<<<NIMG * HH * WW / 256, 256, 0, stream>>>(x, px);
    pack_w_kernel<<<COUT, 256, 0, stream>>>(wt, wg, wsum, alpha);
    conv_kernel<<<NIMG * HH, 256, 0, stream>>>(px, wg, wsum, alpha, out);
}